// Round 1
// baseline (1668.957 us; speedup 1.0000x reference)
//
#include <hip/hip_runtime.h>

#define S_LEN 2048
#define BH 16           // B*C heads
#define LOGIT 768.0f

// ---- workspace layout (floats) ----
#define SZ_HEAD (BH * S_LEN * 96)            // 3,145,728
#define OFF_UR  0
#define OFF_VR  (SZ_HEAD)
#define OFF_UO  (2 * SZ_HEAD)
#define OFF_M   (3 * SZ_HEAD)
#define OFF_L   (3 * SZ_HEAD + BH * S_LEN)
#define OFF_W1  (3 * SZ_HEAD + 2 * BH * S_LEN)
#define OFF_W2  (OFF_W1 + 4096 * 768)
// total = OFF_W2 + 4096*768 = 15,794,176 floats = 63.2 MB

// swizzled transposed-tile index: row d (0..95 or 0..31), col k, width W=64
__device__ __forceinline__ int sw64(int d, int k) {
    return d * 64 + ((((k >> 2) ^ (d & 15)) << 2) | (k & 3));
}
__device__ __forceinline__ int sw32(int d, int k) {
    return d * 32 + ((((k >> 2) ^ (d & 7)) << 2) | (k & 3));
}

// ============================================================
// K1: qz (4096x768) @ U^T and @ V^T -> raw head-major [head][s][r]
// grid (64 bs-tiles, 8 c), block 256
// ============================================================
__global__ __launch_bounds__(256) void k1_proj(const float* __restrict__ qz,
                                               const float* __restrict__ U,
                                               const float* __restrict__ V,
                                               float* __restrict__ uraw,
                                               float* __restrict__ vraw) {
    __shared__ float At[32 * 64];   // qz tile transposed [e][i], swizzled
    __shared__ float Bu[96 * 36];   // U rows natural [j][e]
    __shared__ float Bv[96 * 36];
    const int tid = threadIdx.x;
    const int ty = tid >> 4, tx = tid & 15;
    const int bs0 = blockIdx.x * 64;
    const int c = blockIdx.y;

    float accU[4][6] = {};
    float accV[4][6] = {};

    for (int e0 = 0; e0 < 768; e0 += 32) {
        __syncthreads();
        // stage A transposed+swizzled: 64 rows x 32 e
#pragma unroll
        for (int m = 0; m < 2; ++m) {
            int f = tid + 256 * m;
            int row = f >> 3, c4 = f & 7;
            float4 v = *(const float4*)(qz + (bs0 + row) * 768 + e0 + c4 * 4);
            float vv[4] = {v.x, v.y, v.z, v.w};
#pragma unroll
            for (int dd = 0; dd < 4; ++dd)
                At[sw64(c4 * 4 + dd, row)] = vv[dd];
        }
        // stage Bu/Bv natural: 96 rows x 32 e
#pragma unroll
        for (int m = 0; m < 3; ++m) {
            int f = tid + 256 * m;
            int j = f >> 3, c4 = f & 7;
            float4 vu = *(const float4*)(U + (c * 96 + j) * 768 + e0 + c4 * 4);
            *(float4*)(&Bu[j * 36 + c4 * 4]) = vu;
            float4 vv = *(const float4*)(V + (c * 96 + j) * 768 + e0 + c4 * 4);
            *(float4*)(&Bv[j * 36 + c4 * 4]) = vv;
        }
        __syncthreads();
#pragma unroll 4
        for (int e = 0; e < 32; ++e) {
            float4 a = *(const float4*)(&At[e * 64 + (((ty ^ (e & 15)) << 2))]);
            float av[4] = {a.x, a.y, a.z, a.w};
#pragma unroll
            for (int jj = 0; jj < 6; ++jj) {
                int j = tx + 16 * jj;
                float bu = Bu[j * 36 + e];
                float bv = Bv[j * 36 + e];
#pragma unroll
                for (int ii = 0; ii < 4; ++ii) {
                    accU[ii][jj] = fmaf(av[ii], bu, accU[ii][jj]);
                    accV[ii][jj] = fmaf(av[ii], bv, accV[ii][jj]);
                }
            }
        }
    }
    const int b = bs0 >> 11;
    const int s0 = bs0 & 2047;
    const int head = b * 8 + c;
    const int base = (head * S_LEN) * 96;
#pragma unroll
    for (int ii = 0; ii < 4; ++ii) {
        int s = s0 + ty * 4 + ii;
#pragma unroll
        for (int jj = 0; jj < 6; ++jj) {
            int j = tx + 16 * jj;
            uraw[base + s * 96 + j] = accU[ii][jj];
            vraw[base + s * 96 + j] = accV[ii][jj];
        }
    }
}

// ============================================================
// K1b: RoPE: raw u,v -> ur, vr, uo  (cos[r+48]==cos[r] by construction)
// ============================================================
__global__ __launch_bounds__(256) void k1b_rope(const float* __restrict__ uraw,
                                                const float* __restrict__ vraw,
                                                const float* __restrict__ cosb,
                                                const float* __restrict__ sinb,
                                                float* __restrict__ ur,
                                                float* __restrict__ vr,
                                                float* __restrict__ uo) {
    int p = blockIdx.x * 256 + threadIdx.x;
    if (p >= BH * S_LEN * 48) return;
    int rp = p % 48;
    int hs = p / 48;            // head*2048 + s
    int s = hs & 2047;
    int head = hs >> 11;
    int b = head >> 3;
    int base = hs * 96;
    float u1 = uraw[base + rp], u2 = uraw[base + rp + 48];
    float v1 = vraw[base + rp], v2 = vraw[base + rp + 48];
    int cb = (b * S_LEN + s) * 96 + rp;
    float c_ = cosb[cb], s_ = sinb[cb];
    ur[base + rp]      = u1 * c_ - u2 * s_;
    ur[base + rp + 48] = u2 * c_ + u1 * s_;
    uo[base + rp]      = u1 * c_ + u2 * s_;
    uo[base + rp + 48] = u2 * c_ - u1 * s_;
    vr[base + rp]      = v1 * c_ - v2 * s_;
    vr[base + rp + 48] = v2 * c_ + v1 * s_;
}

// ============================================================
// K2: per-head row stats: M[i]=max_j 768*(ur[i].vr[j]), L[i]=sum exp
// grid (32 q-tiles, 16 heads), block 256
// ============================================================
__global__ __launch_bounds__(256) void k2_stats(const float* __restrict__ ur,
                                                const float* __restrict__ vr,
                                                float* __restrict__ Mo,
                                                float* __restrict__ Lo) {
    __shared__ float At[96 * 64];
    __shared__ float Bt[96 * 64];
    const int tid = threadIdx.x;
    const int ty = tid >> 4, tx = tid & 15;
    const int q0 = blockIdx.x * 64;
    const int head = blockIdx.y;
    const float* urh = ur + head * S_LEN * 96;
    const float* vrh = vr + head * S_LEN * 96;

    // stage A (q-tile) transposed+swizzled
#pragma unroll
    for (int m = 0; m < 6; ++m) {
        int f = tid + 256 * m;
        int row = f / 24, c4 = f % 24;
        float4 v = *(const float4*)(urh + (q0 + row) * 96 + c4 * 4);
        float vv[4] = {v.x, v.y, v.z, v.w};
#pragma unroll
        for (int dd = 0; dd < 4; ++dd)
            At[sw64(c4 * 4 + dd, row)] = vv[dd];
    }

    float m_run[4] = {-3.0e38f, -3.0e38f, -3.0e38f, -3.0e38f};
    float l_run[4] = {0.f, 0.f, 0.f, 0.f};

    for (int k0 = 0; k0 < S_LEN; k0 += 64) {
        __syncthreads();
#pragma unroll
        for (int m = 0; m < 6; ++m) {
            int f = tid + 256 * m;
            int row = f / 24, c4 = f % 24;
            float4 v = *(const float4*)(vrh + (k0 + row) * 96 + c4 * 4);
            float vv[4] = {v.x, v.y, v.z, v.w};
#pragma unroll
            for (int dd = 0; dd < 4; ++dd)
                Bt[sw64(c4 * 4 + dd, row)] = vv[dd];
        }
        __syncthreads();
        float acc[4][4] = {};
#pragma unroll 4
        for (int d = 0; d < 96; ++d) {
            float4 a = *(const float4*)(&At[d * 64 + ((ty ^ (d & 15)) << 2)]);
            float4 bb = *(const float4*)(&Bt[d * 64 + ((tx ^ (d & 15)) << 2)]);
            float av[4] = {a.x, a.y, a.z, a.w};
            float bv[4] = {bb.x, bb.y, bb.z, bb.w};
#pragma unroll
            for (int ii = 0; ii < 4; ++ii)
#pragma unroll
                for (int jj = 0; jj < 4; ++jj)
                    acc[ii][jj] = fmaf(av[ii], bv[jj], acc[ii][jj]);
        }
#pragma unroll
        for (int ii = 0; ii < 4; ++ii) {
            float z0 = LOGIT * acc[ii][0], z1 = LOGIT * acc[ii][1];
            float z2 = LOGIT * acc[ii][2], z3 = LOGIT * acc[ii][3];
            float tmax = fmaxf(fmaxf(z0, z1), fmaxf(z2, z3));
#pragma unroll
            for (int off = 1; off < 16; off <<= 1)
                tmax = fmaxf(tmax, __shfl_xor(tmax, off));
            float ls = __expf(z0 - tmax) + __expf(z1 - tmax) +
                       __expf(z2 - tmax) + __expf(z3 - tmax);
#pragma unroll
            for (int off = 1; off < 16; off <<= 1)
                ls += __shfl_xor(ls, off);
            float nm = fmaxf(m_run[ii], tmax);
            l_run[ii] = l_run[ii] * __expf(m_run[ii] - nm) + ls * __expf(tmax - nm);
            m_run[ii] = nm;
        }
    }
    if (tx == 0) {
#pragma unroll
        for (int ii = 0; ii < 4; ++ii) {
            Mo[head * S_LEN + q0 + ty * 4 + ii] = m_run[ii];
            Lo[head * S_LEN + q0 + ty * 4 + ii] = l_run[ii];
        }
    }
}

// ============================================================
// K3a: out1[q] = sum_k exp(768*ur[q].vr[k]-M[q])/L[q] * vr[k]; rope_o; -> w1
// grid (32 q-tiles, 16 heads), block 256. LDS = exactly 64 KiB.
// ============================================================
__global__ __launch_bounds__(256) void k3a(const float* __restrict__ ur,
                                           const float* __restrict__ vr,
                                           const float* __restrict__ Mo,
                                           const float* __restrict__ Lo,
                                           const float* __restrict__ cosb,
                                           const float* __restrict__ sinb,
                                           float* __restrict__ w1) {
    __shared__ float At[96 * 64];   // ur q-tile, transposed+swizzled
    __shared__ float Bt[96 * 64];   // vr k-tile, transposed+swizzled
    __shared__ float P[64 * 64];
    const int tid = threadIdx.x;
    const int ty = tid >> 4, tx = tid & 15;
    const int q0 = blockIdx.x * 64;
    const int head = blockIdx.y;
    const float* urh = ur + head * S_LEN * 96;
    const float* vrh = vr + head * S_LEN * 96;

#pragma unroll
    for (int m = 0; m < 6; ++m) {
        int f = tid + 256 * m;
        int row = f / 24, c4 = f % 24;
        float4 v = *(const float4*)(urh + (q0 + row) * 96 + c4 * 4);
        float vv[4] = {v.x, v.y, v.z, v.w};
#pragma unroll
        for (int dd = 0; dd < 4; ++dd)
            At[sw64(c4 * 4 + dd, row)] = vv[dd];
    }
    float negM[4], invL[4];
#pragma unroll
    for (int ii = 0; ii < 4; ++ii) {
        negM[ii] = -Mo[head * S_LEN + q0 + 4 * ty + ii];
        invL[ii] = 1.0f / Lo[head * S_LEN + q0 + 4 * ty + ii];
    }
    float out[4][6] = {};

    for (int k0 = 0; k0 < S_LEN; k0 += 64) {
        __syncthreads();
#pragma unroll
        for (int m = 0; m < 6; ++m) {
            int f = tid + 256 * m;
            int row = f / 24, c4 = f % 24;
            float4 v = *(const float4*)(vrh + (k0 + row) * 96 + c4 * 4);
            float vv[4] = {v.x, v.y, v.z, v.w};
#pragma unroll
            for (int dd = 0; dd < 4; ++dd)
                Bt[sw64(c4 * 4 + dd, row)] = vv[dd];
        }
        __syncthreads();
        float acc[4][4] = {};
#pragma unroll 4
        for (int d = 0; d < 96; ++d) {
            float4 a = *(const float4*)(&At[d * 64 + ((ty ^ (d & 15)) << 2)]);
            float4 bb = *(const float4*)(&Bt[d * 64 + ((tx ^ (d & 15)) << 2)]);
            float av[4] = {a.x, a.y, a.z, a.w};
            float bv[4] = {bb.x, bb.y, bb.z, bb.w};
#pragma unroll
            for (int ii = 0; ii < 4; ++ii)
#pragma unroll
                for (int jj = 0; jj < 4; ++jj)
                    acc[ii][jj] = fmaf(av[ii], bv[jj], acc[ii][jj]);
        }
#pragma unroll
        for (int ii = 0; ii < 4; ++ii)
#pragma unroll
            for (int jj = 0; jj < 4; ++jj)
                P[(4 * ty + ii) * 64 + 4 * tx + jj] =
                    __expf(fmaf(LOGIT, acc[ii][jj], negM[ii])) * invL[ii];
        __syncthreads();
#pragma unroll 2
        for (int kt = 0; kt < 64; kt += 4) {
            int kg = kt >> 2;
            float4 p[4], vv[6];
#pragma unroll
            for (int ii = 0; ii < 4; ++ii)
                p[ii] = *(const float4*)&P[(4 * ty + ii) * 64 + kt];
#pragma unroll
            for (int jj = 0; jj < 6; ++jj) {
                int d = tx + 16 * jj;       // d & 15 == tx
                vv[jj] = *(const float4*)&Bt[d * 64 + ((kg ^ tx) << 2)];
            }
#pragma unroll
            for (int ii = 0; ii < 4; ++ii)
#pragma unroll
                for (int jj = 0; jj < 6; ++jj) {
                    out[ii][jj] = fmaf(p[ii].x, vv[jj].x, out[ii][jj]);
                    out[ii][jj] = fmaf(p[ii].y, vv[jj].y, out[ii][jj]);
                    out[ii][jj] = fmaf(p[ii].z, vv[jj].z, out[ii][jj]);
                    out[ii][jj] = fmaf(p[ii].w, vv[jj].w, out[ii][jj]);
                }
        }
        __syncthreads();
    }
    // epilogue: rope_o at position q, write w1[b][q][c*96+r]
    const int b = head >> 3, c = head & 7;
#pragma unroll
    for (int ii = 0; ii < 4; ++ii) {
        int q = q0 + 4 * ty + ii;
        int cb = (b * S_LEN + q) * 96;
        float* wrow = w1 + (b * S_LEN + q) * 768 + c * 96;
#pragma unroll
        for (int jj = 0; jj < 3; ++jj) {
            int r = tx + 16 * jj;
            float c_ = cosb[cb + r], s_ = sinb[cb + r];
            float a = out[ii][jj], b2 = out[ii][jj + 3];
            wrow[r]      = a * c_ + b2 * s_;
            wrow[r + 48] = b2 * c_ - a * s_;
        }
    }
}

// ============================================================
// K3b: out2[q] = sum_k exp(768*vr[q].ur[k]-M[k])/L[k] * uo[k]; rope; -> w2
// grid (32 q-tiles, 16 heads), block 256, k-tile 32. LDS 56 KiB.
// ============================================================
__global__ __launch_bounds__(256) void k3b(const float* __restrict__ ur,
                                           const float* __restrict__ vr,
                                           const float* __restrict__ uo,
                                           const float* __restrict__ Mo,
                                           const float* __restrict__ Lo,
                                           const float* __restrict__ cosb,
                                           const float* __restrict__ sinb,
                                           float* __restrict__ w2) {
    __shared__ float At[96 * 64];   // vr q-tile
    __shared__ float Bt[96 * 32];   // ur k-tile
    __shared__ float Ot[96 * 32];   // uo k-tile
    __shared__ float P[64 * 32];
    const int tid = threadIdx.x;
    const int ty = tid >> 4, tx = tid & 15;
    const int q0 = blockIdx.x * 64;
    const int head = blockIdx.y;
    const float* urh = ur + head * S_LEN * 96;
    const float* vrh = vr + head * S_LEN * 96;
    const float* uoh = uo + head * S_LEN * 96;
    const float* MoH = Mo + head * S_LEN;
    const float* LoH = Lo + head * S_LEN;

#pragma unroll
    for (int m = 0; m < 6; ++m) {
        int f = tid + 256 * m;
        int row = f / 24, c4 = f % 24;
        float4 v = *(const float4*)(vrh + (q0 + row) * 96 + c4 * 4);
        float vv[4] = {v.x, v.y, v.z, v.w};
#pragma unroll
        for (int dd = 0; dd < 4; ++dd)
            At[sw64(c4 * 4 + dd, row)] = vv[dd];
    }
    float out[4][6] = {};

    for (int k0 = 0; k0 < S_LEN; k0 += 32) {
        __syncthreads();
#pragma unroll
        for (int m = 0; m < 3; ++m) {
            int f = tid + 256 * m;
            int row = f / 24, c4 = f % 24;
            float4 v = *(const float4*)(urh + (k0 + row) * 96 + c4 * 4);
            float4 o = *(const float4*)(uoh + (k0 + row) * 96 + c4 * 4);
            float vv[4] = {v.x, v.y, v.z, v.w};
            float ov[4] = {o.x, o.y, o.z, o.w};
#pragma unroll
            for (int dd = 0; dd < 4; ++dd) {
                Bt[sw32(c4 * 4 + dd, row)] = vv[dd];
                Ot[sw32(c4 * 4 + dd, row)] = ov[dd];
            }
        }
        __syncthreads();
        float acc[4][2] = {};
#pragma unroll 4
        for (int d = 0; d < 96; ++d) {
            float4 a = *(const float4*)(&At[d * 64 + ((ty ^ (d & 15)) << 2)]);
            float2 bb = *(const float2*)(&Bt[d * 32 + ((((tx >> 1) ^ (d & 7)) << 2) | ((tx & 1) << 1))]);
            float av[4] = {a.x, a.y, a.z, a.w};
#pragma unroll
            for (int ii = 0; ii < 4; ++ii) {
                acc[ii][0] = fmaf(av[ii], bb.x, acc[ii][0]);
                acc[ii][1] = fmaf(av[ii], bb.y, acc[ii][1]);
            }
        }
#pragma unroll
        for (int jj = 0; jj < 2; ++jj) {
            int kg = k0 + 2 * tx + jj;
            float negM = -MoH[kg];
            float iL = 1.0f / LoH[kg];
#pragma unroll
            for (int ii = 0; ii < 4; ++ii)
                P[(4 * ty + ii) * 32 + 2 * tx + jj] =
                    __expf(fmaf(LOGIT, acc[ii][jj], negM)) * iL;
        }
        __syncthreads();
#pragma unroll 2
        for (int kt = 0; kt < 32; kt += 4) {
            int kg = kt >> 2;
            float4 p[4], vv[6];
#pragma unroll
            for (int ii = 0; ii < 4; ++ii)
                p[ii] = *(const float4*)&P[(4 * ty + ii) * 32 + kt];
#pragma unroll
            for (int jj = 0; jj < 6; ++jj) {
                int d = tx + 16 * jj;       // d & 7 == tx & 7
                vv[jj] = *(const float4*)&Ot[d * 32 + ((kg ^ (tx & 7)) << 2)];
            }
#pragma unroll
            for (int ii = 0; ii < 4; ++ii)
#pragma unroll
                for (int jj = 0; jj < 6; ++jj) {
                    out[ii][jj] = fmaf(p[ii].x, vv[jj].x, out[ii][jj]);
                    out[ii][jj] = fmaf(p[ii].y, vv[jj].y, out[ii][jj]);
                    out[ii][jj] = fmaf(p[ii].z, vv[jj].z, out[ii][jj]);
                    out[ii][jj] = fmaf(p[ii].w, vv[jj].w, out[ii][jj]);
                }
        }
        __syncthreads();
    }
    // epilogue: rope at position q, write w2
    const int b = head >> 3, c = head & 7;
#pragma unroll
    for (int ii = 0; ii < 4; ++ii) {
        int q = q0 + 4 * ty + ii;
        int cb = (b * S_LEN + q) * 96;
        float* wrow = w2 + (b * S_LEN + q) * 768 + c * 96;
#pragma unroll
        for (int jj = 0; jj < 3; ++jj) {
            int r = tx + 16 * jj;
            float c_ = cosb[cb + r], s_ = sinb[cb + r];
            float a = out[ii][jj], b2 = out[ii][jj + 3];
            wrow[r]      = a * c_ - b2 * s_;
            wrow[r + 48] = b2 * c_ + a * s_;
        }
    }
}

// ============================================================
// K4: G = w1 @ U + w2 @ V  -> d_out. grid (64 bs-tiles, 12 d-tiles)
// ============================================================
__global__ __launch_bounds__(256) void k4_final(const float* __restrict__ w1,
                                                const float* __restrict__ w2,
                                                const float* __restrict__ U,
                                                const float* __restrict__ V,
                                                float* __restrict__ outp) {
    __shared__ float A1[32 * 64], A2[32 * 64];  // w tiles transposed [e][i]
    __shared__ float B1[32 * 64], B2[32 * 64];  // U/V tiles natural [e][j]
    const int tid = threadIdx.x;
    const int ty = tid >> 4, tx = tid & 15;
    const int bs0 = blockIdx.x * 64;
    const int d0 = blockIdx.y * 64;
    float acc[4][4] = {};

    for (int e0 = 0; e0 < 768; e0 += 32) {
        __syncthreads();
#pragma unroll
        for (int m = 0; m < 2; ++m) {
            int f = tid + 256 * m;
            int row = f >> 3, c4 = f & 7;
            float4 v1 = *(const float4*)(w1 + (bs0 + row) * 768 + e0 + c4 * 4);
            float4 v2 = *(const float4*)(w2 + (bs0 + row) * 768 + e0 + c4 * 4);
            float a1[4] = {v1.x, v1.y, v1.z, v1.w};
            float a2[4] = {v2.x, v2.y, v2.z, v2.w};
#pragma unroll
            for (int dd = 0; dd < 4; ++dd) {
                A1[sw64(c4 * 4 + dd, row)] = a1[dd];
                A2[sw64(c4 * 4 + dd, row)] = a2[dd];
            }
        }
#pragma unroll
        for (int m = 0; m < 2; ++m) {
            int f = tid + 256 * m;
            int ee = f >> 4, c4 = f & 15;
            float4 bu = *(const float4*)(U + (e0 + ee) * 768 + d0 + c4 * 4);
            *(float4*)(&B1[ee * 64 + c4 * 4]) = bu;
            float4 bv = *(const float4*)(V + (e0 + ee) * 768 + d0 + c4 * 4);
            *(float4*)(&B2[ee * 64 + c4 * 4]) = bv;
        }
        __syncthreads();
#pragma unroll 4
        for (int e = 0; e < 32; ++e) {
            float4 a1 = *(const float4*)(&A1[e * 64 + ((ty ^ (e & 15)) << 2)]);
            float4 a2 = *(const float4*)(&A2[e * 64 + ((ty ^ (e & 15)) << 2)]);
            float4 b1 = *(const float4*)(&B1[e * 64 + tx * 4]);
            float4 b2 = *(const float4*)(&B2[e * 64 + tx * 4]);
            float a1v[4] = {a1.x, a1.y, a1.z, a1.w};
            float a2v[4] = {a2.x, a2.y, a2.z, a2.w};
            float b1v[4] = {b1.x, b1.y, b1.z, b1.w};
            float b2v[4] = {b2.x, b2.y, b2.z, b2.w};
#pragma unroll
            for (int ii = 0; ii < 4; ++ii)
#pragma unroll
                for (int jj = 0; jj < 4; ++jj) {
                    acc[ii][jj] = fmaf(a1v[ii], b1v[jj], acc[ii][jj]);
                    acc[ii][jj] = fmaf(a2v[ii], b2v[jj], acc[ii][jj]);
                }
        }
    }
#pragma unroll
    for (int ii = 0; ii < 4; ++ii) {
        float4 v = {acc[ii][0], acc[ii][1], acc[ii][2], acc[ii][3]};
        *(float4*)(outp + (bs0 + 4 * ty + ii) * 768 + d0 + 4 * tx) = v;
    }
}

extern "C" void kernel_launch(void* const* d_in, const int* in_sizes, int n_in,
                              void* d_out, int out_size, void* d_ws, size_t ws_size,
                              hipStream_t stream) {
    const float* qz   = (const float*)d_in[0];
    const float* cosb = (const float*)d_in[1];
    const float* sinb = (const float*)d_in[2];
    const float* U    = (const float*)d_in[3];
    const float* V    = (const float*)d_in[4];
    float* outp = (float*)d_out;
    float* ws = (float*)d_ws;

    float* ur = ws + OFF_UR;
    float* vr = ws + OFF_VR;
    float* uo = ws + OFF_UO;
    float* Mo = ws + OFF_M;
    float* Lo = ws + OFF_L;
    float* w1 = ws + OFF_W1;   // also holds raw qz_u before rope
    float* w2 = ws + OFF_W2;   // also holds raw qz_v before rope

    k1_proj<<<dim3(64, 8), 256, 0, stream>>>(qz, U, V, w1, w2);
    k1b_rope<<<6144, 256, 0, stream>>>(w1, w2, cosb, sinb, ur, vr, uo);
    k2_stats<<<dim3(32, BH), 256, 0, stream>>>(ur, vr, Mo, Lo);
    k3a<<<dim3(32, BH), 256, 0, stream>>>(ur, vr, Mo, Lo, cosb, sinb, w1);
    k3b<<<dim3(32, BH), 256, 0, stream>>>(ur, vr, uo, Mo, Lo, cosb, sinb, w2);
    k4_final<<<dim3(64, 12), 256, 0, stream>>>(w1, w2, U, V, outp);
}

// Round 2
// 1411.521 us; speedup vs baseline: 1.1824x; 1.1824x over previous
//
#include <hip/hip_runtime.h>

#define S_LEN 2048
#define BH 16           // B*C heads
#define HEAD_STRIDE (96 * 2048)   // floats per head in transposed layout [d][s]

// ---- workspace layout (floats) ----
#define SZ_HEAD (BH * HEAD_STRIDE)            // 3,145,728
#define OFF_UR  0
#define OFF_VR  (SZ_HEAD)
#define OFF_UO  (2 * SZ_HEAD)
#define OFF_M   (3 * SZ_HEAD)
#define OFF_L   (3 * SZ_HEAD + BH * S_LEN)
#define OFF_W1  (3 * SZ_HEAD + 2 * BH * S_LEN)
#define OFF_W2  (OFF_W1 + 4096 * 768)
// total = OFF_W2 + 4096*768 = 15,794,176 floats = 63.2 MB (same as round 1)

// ============================================================
// K1: qz (4096x768) @ U^T, @ V^T + fused RoPE, store TRANSPOSED
// per head: ur_t/vr_t/uo_t [head][r(96)][s(2048)]
// grid (64 bs-tiles, 8 c), block 256
// ============================================================
__global__ __launch_bounds__(256) void k1_proj(const float* __restrict__ qz,
                                               const float* __restrict__ U,
                                               const float* __restrict__ V,
                                               const float* __restrict__ cosb,
                                               const float* __restrict__ sinb,
                                               float* __restrict__ ur_t,
                                               float* __restrict__ vr_t,
                                               float* __restrict__ uo_t) {
    __shared__ float At[64 * 32];   // qz tile natural [i][e], chunk-swizzled
    __shared__ float Bu[96 * 36];   // U rows natural [j][e]
    __shared__ float Bv[96 * 36];
    const int tid = threadIdx.x;
    const int ty = tid >> 4, tx = tid & 15;
    const int bs0 = blockIdx.x * 64;
    const int c = blockIdx.y;

    float accU[4][6] = {};
    float accV[4][6] = {};

    for (int e0 = 0; e0 < 768; e0 += 32) {
        __syncthreads();
        // stage A natural [i][e-chunk swizzled]: b128 writes, contiguous per row
#pragma unroll
        for (int m = 0; m < 2; ++m) {
            int f = tid + 256 * m;
            int i = f >> 3, ec = f & 7;
            float4 v = *(const float4*)(qz + (bs0 + i) * 768 + e0 + 4 * ec);
            *(float4*)&At[i * 32 + ((ec ^ ((i >> 2) & 7)) << 2)] = v;
        }
        // stage Bu/Bv natural [j][e], stride 36
#pragma unroll
        for (int m = 0; m < 3; ++m) {
            int f = tid + 256 * m;
            int j = f >> 3, ec = f & 7;
            *(float4*)&Bu[j * 36 + 4 * ec] =
                *(const float4*)(U + (c * 96 + j) * 768 + e0 + 4 * ec);
            *(float4*)&Bv[j * 36 + 4 * ec] =
                *(const float4*)(V + (c * 96 + j) * 768 + e0 + 4 * ec);
        }
        __syncthreads();
#pragma unroll
        for (int ec = 0; ec < 8; ++ec) {
            float av[4][4];
#pragma unroll
            for (int ii = 0; ii < 4; ++ii) {
                float4 a = *(const float4*)&At[(4 * ty + ii) * 32 + ((ec ^ (ty & 7)) << 2)];
                av[ii][0] = a.x; av[ii][1] = a.y; av[ii][2] = a.z; av[ii][3] = a.w;
            }
#pragma unroll
            for (int jj = 0; jj < 6; ++jj) {
                int j = tx + 16 * jj;
                float4 bu = *(const float4*)&Bu[j * 36 + 4 * ec];
                float4 bv = *(const float4*)&Bv[j * 36 + 4 * ec];
                float buv[4] = {bu.x, bu.y, bu.z, bu.w};
                float bvv[4] = {bv.x, bv.y, bv.z, bv.w};
#pragma unroll
                for (int ee = 0; ee < 4; ++ee)
#pragma unroll
                    for (int ii = 0; ii < 4; ++ii) {
                        accU[ii][jj] = fmaf(av[ii][ee], buv[ee], accU[ii][jj]);
                        accV[ii][jj] = fmaf(av[ii][ee], bvv[ee], accV[ii][jj]);
                    }
            }
        }
    }
    // epilogue: RoPE in registers, transposed float4 stores (s-contiguous)
    const int b = bs0 >> 11;
    const int s0 = bs0 & 2047;
    const int head = b * 8 + c;
    const int base_t = head * HEAD_STRIDE;

    float c_[4][3], s_[4][3];
#pragma unroll
    for (int ii = 0; ii < 4; ++ii) {
        int s = s0 + 4 * ty + ii;
        int cb = (b * S_LEN + s) * 96;
#pragma unroll
        for (int jj = 0; jj < 3; ++jj) {
            c_[ii][jj] = cosb[cb + tx + 16 * jj];
            s_[ii][jj] = sinb[cb + tx + 16 * jj];
        }
    }
    float t[4][6];
    // ur = rope(u)
#pragma unroll
    for (int ii = 0; ii < 4; ++ii)
#pragma unroll
        for (int jj = 0; jj < 3; ++jj) {
            float u1 = accU[ii][jj], u2 = accU[ii][jj + 3];
            t[ii][jj]     = u1 * c_[ii][jj] - u2 * s_[ii][jj];
            t[ii][jj + 3] = u2 * c_[ii][jj] + u1 * s_[ii][jj];
        }
#pragma unroll
    for (int jj = 0; jj < 6; ++jj) {
        float4 o = {t[0][jj], t[1][jj], t[2][jj], t[3][jj]};
        *(float4*)(ur_t + base_t + (tx + 16 * jj) * 2048 + s0 + 4 * ty) = o;
    }
    // uo = rope_o(u)
#pragma unroll
    for (int ii = 0; ii < 4; ++ii)
#pragma unroll
        for (int jj = 0; jj < 3; ++jj) {
            float u1 = accU[ii][jj], u2 = accU[ii][jj + 3];
            t[ii][jj]     = u1 * c_[ii][jj] + u2 * s_[ii][jj];
            t[ii][jj + 3] = u2 * c_[ii][jj] - u1 * s_[ii][jj];
        }
#pragma unroll
    for (int jj = 0; jj < 6; ++jj) {
        float4 o = {t[0][jj], t[1][jj], t[2][jj], t[3][jj]};
        *(float4*)(uo_t + base_t + (tx + 16 * jj) * 2048 + s0 + 4 * ty) = o;
    }
    // vr = rope(v)
#pragma unroll
    for (int ii = 0; ii < 4; ++ii)
#pragma unroll
        for (int jj = 0; jj < 3; ++jj) {
            float v1 = accV[ii][jj], v2 = accV[ii][jj + 3];
            t[ii][jj]     = v1 * c_[ii][jj] - v2 * s_[ii][jj];
            t[ii][jj + 3] = v2 * c_[ii][jj] + v1 * s_[ii][jj];
        }
#pragma unroll
    for (int jj = 0; jj < 6; ++jj) {
        float4 o = {t[0][jj], t[1][jj], t[2][jj], t[3][jj]};
        *(float4*)(vr_t + base_t + (tx + 16 * jj) * 2048 + s0 + 4 * ty) = o;
    }
}

// ---- shared helpers (inlined pattern): stage a [96][64] tile from
// transposed global (row stride 2048) into LDS, chunk-swizzled ----
#define STAGE_TILE(dst, srcbase, col0)                                        \
    _Pragma("unroll")                                                         \
    for (int m = 0; m < 6; ++m) {                                             \
        int f = tid + 256 * m;                                                \
        int d = f >> 4, kc = f & 15;                                          \
        float4 v = *(const float4*)((srcbase) + d * 2048 + (col0) + 4 * kc);  \
        *(float4*)&dst[d * 64 + ((kc ^ (d & 7)) << 2)] = v;                   \
    }

// ============================================================
// K2: per-head row stats of z[i][j] = 768*(ur_i . vr_j)
// grid (32 q-tiles, 16 heads), block 256
// ============================================================
__global__ __launch_bounds__(256) void k2_stats(const float* __restrict__ ur_t,
                                                const float* __restrict__ vr_t,
                                                float* __restrict__ Mo,
                                                float* __restrict__ Lo) {
    __shared__ float At[96 * 64];
    __shared__ float Bt[96 * 64];
    const int tid = threadIdx.x;
    const int ty = tid >> 4, tx = tid & 15;
    const int q0 = blockIdx.x * 64;
    const int head = blockIdx.y;
    const float* A = ur_t + head * HEAD_STRIDE;
    const float* Bg = vr_t + head * HEAD_STRIDE;

    STAGE_TILE(At, A, q0)

    float m_run[4] = {-3.0e38f, -3.0e38f, -3.0e38f, -3.0e38f};
    float l_run[4] = {0.f, 0.f, 0.f, 0.f};

    for (int k0 = 0; k0 < S_LEN; k0 += 64) {
        __syncthreads();
        STAGE_TILE(Bt, Bg, k0)
        __syncthreads();
        float acc[4][4] = {};
#pragma unroll 4
        for (int d = 0; d < 96; ++d) {
            float4 a = *(const float4*)&At[d * 64 + ((ty ^ (d & 7)) << 2)];
            float4 bb = *(const float4*)&Bt[d * 64 + ((tx ^ (d & 7)) << 2)];
            float av[4] = {a.x, a.y, a.z, a.w};
            float bv[4] = {bb.x, bb.y, bb.z, bb.w};
#pragma unroll
            for (int ii = 0; ii < 4; ++ii)
#pragma unroll
                for (int jj = 0; jj < 4; ++jj)
                    acc[ii][jj] = fmaf(av[ii], bv[jj], acc[ii][jj]);
        }
#pragma unroll
        for (int ii = 0; ii < 4; ++ii) {
            float z0 = 768.0f * acc[ii][0], z1 = 768.0f * acc[ii][1];
            float z2 = 768.0f * acc[ii][2], z3 = 768.0f * acc[ii][3];
            float tmax = fmaxf(fmaxf(z0, z1), fmaxf(z2, z3));
#pragma unroll
            for (int off = 1; off < 16; off <<= 1)
                tmax = fmaxf(tmax, __shfl_xor(tmax, off));
            float ls = __expf(z0 - tmax) + __expf(z1 - tmax) +
                       __expf(z2 - tmax) + __expf(z3 - tmax);
#pragma unroll
            for (int off = 1; off < 16; off <<= 1)
                ls += __shfl_xor(ls, off);
            float nm = fmaxf(m_run[ii], tmax);
            l_run[ii] = l_run[ii] * __expf(m_run[ii] - nm) + ls * __expf(tmax - nm);
            m_run[ii] = nm;
        }
    }
    if (tx == 0) {
#pragma unroll
        for (int ii = 0; ii < 4; ++ii) {
            Mo[head * S_LEN + q0 + ty * 4 + ii] = m_run[ii];
            Lo[head * S_LEN + q0 + ty * 4 + ii] = l_run[ii];
        }
    }
}

// ============================================================
// K3a: out1[q] = sum_k P[q,k]*vr[k], P row-normalized; rope_o -> w1
// grid (32 q-tiles, 16 heads), block 256. LDS = 64 KiB exactly.
// ============================================================
__global__ __launch_bounds__(256) void k3a(const float* __restrict__ ur_t,
                                           const float* __restrict__ vr_t,
                                           const float* __restrict__ Mo,
                                           const float* __restrict__ Lo,
                                           const float* __restrict__ cosb,
                                           const float* __restrict__ sinb,
                                           float* __restrict__ w1) {
    __shared__ float At[96 * 64];
    __shared__ float Bt[96 * 64];
    __shared__ float P[64 * 64];
    const int tid = threadIdx.x;
    const int ty = tid >> 4, tx = tid & 15;
    const int q0 = blockIdx.x * 64;
    const int head = blockIdx.y;
    const float* A = ur_t + head * HEAD_STRIDE;
    const float* Bg = vr_t + head * HEAD_STRIDE;

    STAGE_TILE(At, A, q0)

    float negM[4], invL[4];
#pragma unroll
    for (int ii = 0; ii < 4; ++ii) {
        negM[ii] = -Mo[head * S_LEN + q0 + 4 * ty + ii];
        invL[ii] = 1.0f / Lo[head * S_LEN + q0 + 4 * ty + ii];
    }
    float out[4][6] = {};

    for (int k0 = 0; k0 < S_LEN; k0 += 64) {
        __syncthreads();
        STAGE_TILE(Bt, Bg, k0)
        __syncthreads();
        float acc[4][4] = {};
#pragma unroll 4
        for (int d = 0; d < 96; ++d) {
            float4 a = *(const float4*)&At[d * 64 + ((ty ^ (d & 7)) << 2)];
            float4 bb = *(const float4*)&Bt[d * 64 + ((tx ^ (d & 7)) << 2)];
            float av[4] = {a.x, a.y, a.z, a.w};
            float bv[4] = {bb.x, bb.y, bb.z, bb.w};
#pragma unroll
            for (int ii = 0; ii < 4; ++ii)
#pragma unroll
                for (int jj = 0; jj < 4; ++jj)
                    acc[ii][jj] = fmaf(av[ii], bv[jj], acc[ii][jj]);
        }
#pragma unroll
        for (int ii = 0; ii < 4; ++ii) {
            int qp = 4 * ty + ii;
            float4 p4;
            p4.x = __expf(768.0f * acc[ii][0] + negM[ii]) * invL[ii];
            p4.y = __expf(768.0f * acc[ii][1] + negM[ii]) * invL[ii];
            p4.z = __expf(768.0f * acc[ii][2] + negM[ii]) * invL[ii];
            p4.w = __expf(768.0f * acc[ii][3] + negM[ii]) * invL[ii];
            *(float4*)&P[qp * 64 + ((tx ^ (qp & 7)) << 2)] = p4;
        }
        __syncthreads();
#pragma unroll 4
        for (int kg = 0; kg < 16; ++kg) {
            float4 p[4];
#pragma unroll
            for (int ii = 0; ii < 4; ++ii) {
                int qp = 4 * ty + ii;
                p[ii] = *(const float4*)&P[qp * 64 + ((kg ^ (qp & 7)) << 2)];
            }
#pragma unroll
            for (int jj = 0; jj < 6; ++jj) {
                float4 vv = *(const float4*)&Bt[(tx + 16 * jj) * 64 + ((kg ^ (tx & 7)) << 2)];
#pragma unroll
                for (int ii = 0; ii < 4; ++ii) {
                    out[ii][jj] = fmaf(p[ii].x, vv.x, out[ii][jj]);
                    out[ii][jj] = fmaf(p[ii].y, vv.y, out[ii][jj]);
                    out[ii][jj] = fmaf(p[ii].z, vv.z, out[ii][jj]);
                    out[ii][jj] = fmaf(p[ii].w, vv.w, out[ii][jj]);
                }
            }
        }
        __syncthreads();
    }
    // epilogue: rope_o at q, write w1[b][q][c*96+r]
    const int b = head >> 3, c = head & 7;
#pragma unroll
    for (int ii = 0; ii < 4; ++ii) {
        int q = q0 + 4 * ty + ii;
        int cb = (b * S_LEN + q) * 96;
        float* wrow = w1 + (b * S_LEN + q) * 768 + c * 96;
#pragma unroll
        for (int jj = 0; jj < 3; ++jj) {
            int r = tx + 16 * jj;
            float cc = cosb[cb + r], ss = sinb[cb + r];
            float a = out[ii][jj], b2 = out[ii][jj + 3];
            wrow[r]      = a * cc + b2 * ss;
            wrow[r + 48] = b2 * cc - a * ss;
        }
    }
}

// ============================================================
// K3b: out2[q] = sum_k P^T[q,k]*uo[k], P col-normalized (M[k],L[k]);
// rope -> w2.  Same shape as k3a; Bt double-staged (ur then uo).
// ============================================================
__global__ __launch_bounds__(256) void k3b(const float* __restrict__ ur_t,
                                           const float* __restrict__ vr_t,
                                           const float* __restrict__ uo_t,
                                           const float* __restrict__ Mo,
                                           const float* __restrict__ Lo,
                                           const float* __restrict__ cosb,
                                           const float* __restrict__ sinb,
                                           float* __restrict__ w2) {
    __shared__ float At[96 * 64];
    __shared__ float Bt[96 * 64];
    __shared__ float P[64 * 64];
    const int tid = threadIdx.x;
    const int ty = tid >> 4, tx = tid & 15;
    const int q0 = blockIdx.x * 64;
    const int head = blockIdx.y;
    const float* A = vr_t + head * HEAD_STRIDE;
    const float* Bg = ur_t + head * HEAD_STRIDE;
    const float* Og = uo_t + head * HEAD_STRIDE;
    const float* MoH = Mo + head * S_LEN;
    const float* LoH = Lo + head * S_LEN;

    STAGE_TILE(At, A, q0)

    float out[4][6] = {};

    for (int k0 = 0; k0 < S_LEN; k0 += 64) {
        float negMk[4], invLk[4];
#pragma unroll
        for (int jj = 0; jj < 4; ++jj) {
            negMk[jj] = -MoH[k0 + 4 * tx + jj];
            invLk[jj] = 1.0f / LoH[k0 + 4 * tx + jj];
        }
        __syncthreads();
        STAGE_TILE(Bt, Bg, k0)
        __syncthreads();
        float acc[4][4] = {};
#pragma unroll 4
        for (int d = 0; d < 96; ++d) {
            float4 a = *(const float4*)&At[d * 64 + ((ty ^ (d & 7)) << 2)];
            float4 bb = *(const float4*)&Bt[d * 64 + ((tx ^ (d & 7)) << 2)];
            float av[4] = {a.x, a.y, a.z, a.w};
            float bv[4] = {bb.x, bb.y, bb.z, bb.w};
#pragma unroll
            for (int ii = 0; ii < 4; ++ii)
#pragma unroll
                for (int jj = 0; jj < 4; ++jj)
                    acc[ii][jj] = fmaf(av[ii], bv[jj], acc[ii][jj]);
        }
#pragma unroll
        for (int ii = 0; ii < 4; ++ii) {
            int qp = 4 * ty + ii;
            float4 p4;
            p4.x = __expf(768.0f * acc[ii][0] + negMk[0]) * invLk[0];
            p4.y = __expf(768.0f * acc[ii][1] + negMk[1]) * invLk[1];
            p4.z = __expf(768.0f * acc[ii][2] + negMk[2]) * invLk[2];
            p4.w = __expf(768.0f * acc[ii][3] + negMk[3]) * invLk[3];
            *(float4*)&P[qp * 64 + ((tx ^ (qp & 7)) << 2)] = p4;
        }
        __syncthreads();
        STAGE_TILE(Bt, Og, k0)    // overwrite Bt with uo k-tile
        __syncthreads();
#pragma unroll 4
        for (int kg = 0; kg < 16; ++kg) {
            float4 p[4];
#pragma unroll
            for (int ii = 0; ii < 4; ++ii) {
                int qp = 4 * ty + ii;
                p[ii] = *(const float4*)&P[qp * 64 + ((kg ^ (qp & 7)) << 2)];
            }
#pragma unroll
            for (int jj = 0; jj < 6; ++jj) {
                float4 vv = *(const float4*)&Bt[(tx + 16 * jj) * 64 + ((kg ^ (tx & 7)) << 2)];
#pragma unroll
                for (int ii = 0; ii < 4; ++ii) {
                    out[ii][jj] = fmaf(p[ii].x, vv.x, out[ii][jj]);
                    out[ii][jj] = fmaf(p[ii].y, vv.y, out[ii][jj]);
                    out[ii][jj] = fmaf(p[ii].z, vv.z, out[ii][jj]);
                    out[ii][jj] = fmaf(p[ii].w, vv.w, out[ii][jj]);
                }
            }
        }
        __syncthreads();
    }
    // epilogue: rope at q, write w2
    const int b = head >> 3, c = head & 7;
#pragma unroll
    for (int ii = 0; ii < 4; ++ii) {
        int q = q0 + 4 * ty + ii;
        int cb = (b * S_LEN + q) * 96;
        float* wrow = w2 + (b * S_LEN + q) * 768 + c * 96;
#pragma unroll
        for (int jj = 0; jj < 3; ++jj) {
            int r = tx + 16 * jj;
            float cc = cosb[cb + r], ss = sinb[cb + r];
            float a = out[ii][jj], b2 = out[ii][jj + 3];
            wrow[r]      = a * cc - b2 * ss;
            wrow[r + 48] = b2 * cc + a * ss;
        }
    }
}

// ============================================================
// K4: G = w1 @ U + w2 @ V  -> d_out. grid (64 bs-tiles, 12 d-tiles)
// ============================================================
__global__ __launch_bounds__(256) void k4_final(const float* __restrict__ w1,
                                                const float* __restrict__ w2,
                                                const float* __restrict__ U,
                                                const float* __restrict__ V,
                                                float* __restrict__ outp) {
    __shared__ float A1[64 * 32], A2[64 * 32];  // w tiles natural [i][e], swizzled
    __shared__ float B1[32 * 64], B2[32 * 64];  // U/V tiles natural [e][j]
    const int tid = threadIdx.x;
    const int ty = tid >> 4, tx = tid & 15;
    const int bs0 = blockIdx.x * 64;
    const int d0 = blockIdx.y * 64;
    float acc[4][4] = {};

    for (int e0 = 0; e0 < 768; e0 += 32) {
        __syncthreads();
#pragma unroll
        for (int m = 0; m < 2; ++m) {
            int f = tid + 256 * m;
            int i = f >> 3, ec = f & 7;
            int sw = i * 32 + ((ec ^ ((i >> 2) & 7)) << 2);
            *(float4*)&A1[sw] = *(const float4*)(w1 + (bs0 + i) * 768 + e0 + 4 * ec);
            *(float4*)&A2[sw] = *(const float4*)(w2 + (bs0 + i) * 768 + e0 + 4 * ec);
        }
#pragma unroll
        for (int m = 0; m < 2; ++m) {
            int f = tid + 256 * m;
            int ee = f >> 4, jc = f & 15;
            *(float4*)&B1[ee * 64 + 4 * jc] =
                *(const float4*)(U + (e0 + ee) * 768 + d0 + 4 * jc);
            *(float4*)&B2[ee * 64 + 4 * jc] =
                *(const float4*)(V + (e0 + ee) * 768 + d0 + 4 * jc);
        }
        __syncthreads();
#pragma unroll
        for (int ec = 0; ec < 8; ++ec) {
            float a1v[4][4], a2v[4][4];
#pragma unroll
            for (int ii = 0; ii < 4; ++ii) {
                int sw = (4 * ty + ii) * 32 + ((ec ^ (ty & 7)) << 2);
                float4 a1 = *(const float4*)&A1[sw];
                float4 a2 = *(const float4*)&A2[sw];
                a1v[ii][0] = a1.x; a1v[ii][1] = a1.y; a1v[ii][2] = a1.z; a1v[ii][3] = a1.w;
                a2v[ii][0] = a2.x; a2v[ii][1] = a2.y; a2v[ii][2] = a2.z; a2v[ii][3] = a2.w;
            }
#pragma unroll
            for (int ee = 0; ee < 4; ++ee) {
                int e = 4 * ec + ee;
                float4 b1 = *(const float4*)&B1[e * 64 + 4 * tx];
                float4 b2 = *(const float4*)&B2[e * 64 + 4 * tx];
                float b1v[4] = {b1.x, b1.y, b1.z, b1.w};
                float b2v[4] = {b2.x, b2.y, b2.z, b2.w};
#pragma unroll
                for (int ii = 0; ii < 4; ++ii)
#pragma unroll
                    for (int jj = 0; jj < 4; ++jj) {
                        acc[ii][jj] = fmaf(a1v[ii][ee], b1v[jj], acc[ii][jj]);
                        acc[ii][jj] = fmaf(a2v[ii][ee], b2v[jj], acc[ii][jj]);
                    }
            }
        }
    }
#pragma unroll
    for (int ii = 0; ii < 4; ++ii) {
        float4 v = {acc[ii][0], acc[ii][1], acc[ii][2], acc[ii][3]};
        *(float4*)(outp + (bs0 + 4 * ty + ii) * 768 + d0 + 4 * tx) = v;
    }
}

extern "C" void kernel_launch(void* const* d_in, const int* in_sizes, int n_in,
                              void* d_out, int out_size, void* d_ws, size_t ws_size,
                              hipStream_t stream) {
    const float* qz   = (const float*)d_in[0];
    const float* cosb = (const float*)d_in[1];
    const float* sinb = (const float*)d_in[2];
    const float* U    = (const float*)d_in[3];
    const float* V    = (const float*)d_in[4];
    float* outp = (float*)d_out;
    float* ws = (float*)d_ws;

    float* ur_t = ws + OFF_UR;
    float* vr_t = ws + OFF_VR;
    float* uo_t = ws + OFF_UO;
    float* Mo = ws + OFF_M;
    float* Lo = ws + OFF_L;
    float* w1 = ws + OFF_W1;
    float* w2 = ws + OFF_W2;

    k1_proj<<<dim3(64, 8), 256, 0, stream>>>(qz, U, V, cosb, sinb, ur_t, vr_t, uo_t);
    k2_stats<<<dim3(32, BH), 256, 0, stream>>>(ur_t, vr_t, Mo, Lo);
    k3a<<<dim3(32, BH), 256, 0, stream>>>(ur_t, vr_t, Mo, Lo, cosb, sinb, w1);
    k3b<<<dim3(32, BH), 256, 0, stream>>>(ur_t, vr_t, uo_t, Mo, Lo, cosb, sinb, w2);
    k4_final<<<dim3(64, 12), 256, 0, stream>>>(w1, w2, U, V, outp);
}

// Round 3
// 569.682 us; speedup vs baseline: 2.9296x; 2.4777x over previous
//
#include <hip/hip_runtime.h>

typedef _Float16 f16;
typedef _Float16 f16x8 __attribute__((ext_vector_type(8)));
typedef _Float16 f16x4 __attribute__((ext_vector_type(4)));
typedef float f32x4 __attribute__((ext_vector_type(4)));

#define MFMA16(A,B,C) __builtin_amdgcn_mfma_f32_16x16x32_f16(A,B,C,0,0,0)
#define INV2048 4.8828125e-4f
#define HN (16ll*2048*96)

__device__ __forceinline__ void split_f16(float x, f16& h, f16& l) {
    h = (f16)x;
    l = (f16)((x - (float)h) * 2048.0f);   // lo pre-scaled by 2^11 (avoids fp16 denorm loss)
}
__device__ __forceinline__ float rmax16(float v) {
    v = fmaxf(v, __shfl_xor(v, 1)); v = fmaxf(v, __shfl_xor(v, 2));
    v = fmaxf(v, __shfl_xor(v, 4)); v = fmaxf(v, __shfl_xor(v, 8));
    return v;
}
__device__ __forceinline__ float rsum16(float v) {
    v += __shfl_xor(v, 1); v += __shfl_xor(v, 2);
    v += __shfl_xor(v, 4); v += __shfl_xor(v, 8);
    return v;
}

// ============================================================
// K1: fp32 dual GEMM qz@U^T, qz@V^T + RoPE; emit fp16 hi/lo natural
// [head][s][96] for ur,vr; fp16-hi transposed [head][96][s] for vr,uo.
// grid (64 bs-tiles, 8 c), block 256
// ============================================================
__global__ __launch_bounds__(256) void k1_proj(const float* __restrict__ qz,
                                               const float* __restrict__ U,
                                               const float* __restrict__ V,
                                               const float* __restrict__ cosb,
                                               const float* __restrict__ sinb,
                                               f16* __restrict__ uhp, f16* __restrict__ ulp,
                                               f16* __restrict__ vhp, f16* __restrict__ vlp,
                                               f16* __restrict__ vT, f16* __restrict__ oT) {
    __shared__ float At[64 * 32];
    __shared__ float Bu[96 * 36];
    __shared__ float Bv[96 * 36];
    const int tid = threadIdx.x;
    const int ty = tid >> 4, tx = tid & 15;
    const int bs0 = blockIdx.x * 64;
    const int c = blockIdx.y;

    float accU[4][6] = {};
    float accV[4][6] = {};

    for (int e0 = 0; e0 < 768; e0 += 32) {
        __syncthreads();
#pragma unroll
        for (int m = 0; m < 2; ++m) {
            int f = tid + 256 * m;
            int i = f >> 3, ec = f & 7;
            float4 v = *(const float4*)(qz + (bs0 + i) * 768 + e0 + 4 * ec);
            *(float4*)&At[i * 32 + ((ec ^ ((i >> 2) & 7)) << 2)] = v;
        }
#pragma unroll
        for (int m = 0; m < 3; ++m) {
            int f = tid + 256 * m;
            int j = f >> 3, ec = f & 7;
            *(float4*)&Bu[j * 36 + 4 * ec] =
                *(const float4*)(U + (c * 96 + j) * 768 + e0 + 4 * ec);
            *(float4*)&Bv[j * 36 + 4 * ec] =
                *(const float4*)(V + (c * 96 + j) * 768 + e0 + 4 * ec);
        }
        __syncthreads();
#pragma unroll
        for (int ec = 0; ec < 8; ++ec) {
            float av[4][4];
#pragma unroll
            for (int ii = 0; ii < 4; ++ii) {
                float4 a = *(const float4*)&At[(4 * ty + ii) * 32 + ((ec ^ (ty & 7)) << 2)];
                av[ii][0] = a.x; av[ii][1] = a.y; av[ii][2] = a.z; av[ii][3] = a.w;
            }
#pragma unroll
            for (int jj = 0; jj < 6; ++jj) {
                int j = tx + 16 * jj;
                float4 bu = *(const float4*)&Bu[j * 36 + 4 * ec];
                float4 bv = *(const float4*)&Bv[j * 36 + 4 * ec];
                float buv[4] = {bu.x, bu.y, bu.z, bu.w};
                float bvv[4] = {bv.x, bv.y, bv.z, bv.w};
#pragma unroll
                for (int ee = 0; ee < 4; ++ee)
#pragma unroll
                    for (int ii = 0; ii < 4; ++ii) {
                        accU[ii][jj] = fmaf(av[ii][ee], buv[ee], accU[ii][jj]);
                        accV[ii][jj] = fmaf(av[ii][ee], bvv[ee], accV[ii][jj]);
                    }
            }
        }
    }
    const int b = bs0 >> 11;
    const int s0 = bs0 & 2047;
    const int head = b * 8 + c;
    const size_t nb = (size_t)head * 2048 * 96;
    const size_t tb = (size_t)head * 96 * 2048;

#pragma unroll
    for (int jj = 0; jj < 3; ++jj) {
        int r = tx + 16 * jj;
        f16 vt1[4], vt2[4], ot1[4], ot2[4];
#pragma unroll
        for (int ii = 0; ii < 4; ++ii) {
            int s = s0 + 4 * ty + ii;
            int cbi = (b * 2048 + s) * 96 + r;
            float cc = cosb[cbi], ss = sinb[cbi];
            size_t rowb = nb + (size_t)s * 96;
            float u1 = accU[ii][jj], u2 = accU[ii][jj + 3];
            float v1 = accV[ii][jj], v2 = accV[ii][jj + 3];
            float ur1 = u1 * cc - u2 * ss, ur2 = u2 * cc + u1 * ss;
            float uo1 = u1 * cc + u2 * ss, uo2 = u2 * cc - u1 * ss;
            float vr1 = v1 * cc - v2 * ss, vr2 = v2 * cc + v1 * ss;
            f16 h, l;
            split_f16(ur1, h, l); uhp[rowb + r] = h;      ulp[rowb + r] = l;
            split_f16(ur2, h, l); uhp[rowb + r + 48] = h; ulp[rowb + r + 48] = l;
            split_f16(vr1, h, l); vhp[rowb + r] = h;      vlp[rowb + r] = l;      vt1[ii] = h;
            split_f16(vr2, h, l); vhp[rowb + r + 48] = h; vlp[rowb + r + 48] = l; vt2[ii] = h;
            ot1[ii] = (f16)uo1; ot2[ii] = (f16)uo2;
        }
        f16x4 pv1 = {vt1[0], vt1[1], vt1[2], vt1[3]};
        f16x4 pv2 = {vt2[0], vt2[1], vt2[2], vt2[3]};
        f16x4 po1 = {ot1[0], ot1[1], ot1[2], ot1[3]};
        f16x4 po2 = {ot2[0], ot2[1], ot2[2], ot2[3]};
        *(f16x4*)&vT[tb + (size_t)r * 2048 + s0 + 4 * ty] = pv1;
        *(f16x4*)&vT[tb + (size_t)(r + 48) * 2048 + s0 + 4 * ty] = pv2;
        *(f16x4*)&oT[tb + (size_t)r * 2048 + s0 + 4 * ty] = po1;
        *(f16x4*)&oT[tb + (size_t)(r + 48) * 2048 + s0 + 4 * ty] = po2;
    }
}

// ============================================================
// K2: MFMA row stats. grid (32 qtiles, 16 heads), block 256 (4 waves).
// Wave w owns k-strip w*16 of each 64-k tile; A(q) frags in regs.
// ============================================================
__global__ __launch_bounds__(256, 2) void k2_stats(const f16* __restrict__ uhp,
                                                   const f16* __restrict__ ulp,
                                                   const f16* __restrict__ vhp,
                                                   const f16* __restrict__ vlp,
                                                   float* __restrict__ Mo,
                                                   float* __restrict__ Lo) {
    __shared__ f16 Bh[64 * 104];
    __shared__ f16 Bl[64 * 104];
    __shared__ float Mbuf[4][64], Lbuf[4][64];
    const int tid = threadIdx.x, w = tid >> 6, lane = tid & 63;
    const int quad = lane >> 4, l15 = lane & 15;
    const int q0 = blockIdx.x * 64, head = blockIdx.y;
    const f16* Ah_g = uhp + (size_t)head * 2048 * 96;
    const f16* Al_g = ulp + (size_t)head * 2048 * 96;
    const f16* Bh_g = vhp + (size_t)head * 2048 * 96;
    const f16* Bl_g = vlp + (size_t)head * 2048 * 96;

    f16x8 Afh[4][3], Afl[4][3];
#pragma unroll
    for (int mt = 0; mt < 4; ++mt)
#pragma unroll
        for (int cc = 0; cc < 3; ++cc) {
            size_t off = (size_t)(q0 + 16 * mt + l15) * 96 + cc * 32 + quad * 8;
            Afh[mt][cc] = *(const f16x8*)(Ah_g + off);
            Afl[mt][cc] = *(const f16x8*)(Al_g + off);
        }

    float m_run[4][4], l_run[4][4];
#pragma unroll
    for (int mt = 0; mt < 4; ++mt)
#pragma unroll
        for (int r = 0; r < 4; ++r) { m_run[mt][r] = -3.0e38f; l_run[mt][r] = 0.f; }

    for (int k0 = 0; k0 < 2048; k0 += 64) {
        __syncthreads();
#pragma unroll
        for (int m = 0; m < 3; ++m) {
            int f = tid + 256 * m;
            int row = f / 12, c12 = f % 12;
            *(float4*)&Bh[row * 104 + c12 * 8] =
                *(const float4*)(Bh_g + (size_t)(k0 + row) * 96 + c12 * 8);
            *(float4*)&Bl[row * 104 + c12 * 8] =
                *(const float4*)(Bl_g + (size_t)(k0 + row) * 96 + c12 * 8);
        }
        __syncthreads();
        f32x4 accS[4] = {}, accX[4] = {};
#pragma unroll
        for (int cc = 0; cc < 3; ++cc) {
            f16x8 bh = *(const f16x8*)&Bh[(w * 16 + l15) * 104 + cc * 32 + quad * 8];
            f16x8 bl = *(const f16x8*)&Bl[(w * 16 + l15) * 104 + cc * 32 + quad * 8];
#pragma unroll
            for (int mt = 0; mt < 4; ++mt) {
                accS[mt] = MFMA16(Afh[mt][cc], bh, accS[mt]);
                accX[mt] = MFMA16(Afh[mt][cc], bl, accX[mt]);
                accX[mt] = MFMA16(Afl[mt][cc], bh, accX[mt]);
            }
        }
#pragma unroll
        for (int mt = 0; mt < 4; ++mt)
#pragma unroll
            for (int r = 0; r < 4; ++r) {
                float z = 768.0f * (accS[mt][r] + accX[mt][r] * INV2048);
                float tm = rmax16(z);
                float e = rsum16(__expf(z - tm));
                float nm = fmaxf(m_run[mt][r], tm);
                l_run[mt][r] = l_run[mt][r] * __expf(m_run[mt][r] - nm) + e * __expf(tm - nm);
                m_run[mt][r] = nm;
            }
    }
    if (l15 == 0) {
#pragma unroll
        for (int mt = 0; mt < 4; ++mt)
#pragma unroll
            for (int r = 0; r < 4; ++r) {
                Mbuf[w][16 * mt + 4 * quad + r] = m_run[mt][r];
                Lbuf[w][16 * mt + 4 * quad + r] = l_run[mt][r];
            }
    }
    __syncthreads();
    if (tid < 64) {
        float M = -3.0e38f;
#pragma unroll
        for (int ww = 0; ww < 4; ++ww) M = fmaxf(M, Mbuf[ww][tid]);
        float L = 0.f;
#pragma unroll
        for (int ww = 0; ww < 4; ++ww) L += Lbuf[ww][tid] * __expf(Mbuf[ww][tid] - M);
        Mo[head * 2048 + q0 + tid] = M;
        Lo[head * 2048 + q0 + tid] = L;
    }
}

// ============================================================
// K3a: S=ur.vr^T (x3 fp16 emulation, bitwise == k2), P=exp(z-M[q]),
// out=P@vr (fp16 PV), scale 1/L[q], rope_o -> w1 (f16).
// ============================================================
__global__ __launch_bounds__(256, 2) void k3a(const f16* __restrict__ uhp,
                                              const f16* __restrict__ ulp,
                                              const f16* __restrict__ vhp,
                                              const f16* __restrict__ vlp,
                                              const f16* __restrict__ vT,
                                              const float* __restrict__ Mo,
                                              const float* __restrict__ Lo,
                                              const float* __restrict__ cosb,
                                              const float* __restrict__ sinb,
                                              f16* __restrict__ w1) {
    __shared__ f16 Bh[64 * 104];
    __shared__ f16 Bl[64 * 104];
    __shared__ f16 Vt[96 * 72];
    __shared__ f16 P[64 * 72];
    const int tid = threadIdx.x, w = tid >> 6, lane = tid & 63;
    const int quad = lane >> 4, l15 = lane & 15;
    const int q0 = blockIdx.x * 64, head = blockIdx.y;
    const f16* Ah_g = uhp + (size_t)head * 2048 * 96;
    const f16* Al_g = ulp + (size_t)head * 2048 * 96;
    const f16* Bh_g = vhp + (size_t)head * 2048 * 96;
    const f16* Bl_g = vlp + (size_t)head * 2048 * 96;
    const f16* Vt_g = vT + (size_t)head * 96 * 2048;

    f16x8 Afh[4][3], Afl[4][3];
#pragma unroll
    for (int mt = 0; mt < 4; ++mt)
#pragma unroll
        for (int cc = 0; cc < 3; ++cc) {
            size_t off = (size_t)(q0 + 16 * mt + l15) * 96 + cc * 32 + quad * 8;
            Afh[mt][cc] = *(const f16x8*)(Ah_g + off);
            Afl[mt][cc] = *(const f16x8*)(Al_g + off);
        }
    float negM[4][4];
#pragma unroll
    for (int mt = 0; mt < 4; ++mt)
#pragma unroll
        for (int r = 0; r < 4; ++r)
            negM[mt][r] = -Mo[head * 2048 + q0 + 16 * mt + 4 * quad + r];
    float invL[4];
#pragma unroll
    for (int r = 0; r < 4; ++r)
        invL[r] = 1.0f / Lo[head * 2048 + q0 + w * 16 + quad * 4 + r];

    f32x4 accO[6] = {};

    for (int k0 = 0; k0 < 2048; k0 += 64) {
        __syncthreads();
#pragma unroll
        for (int m = 0; m < 3; ++m) {
            int f = tid + 256 * m;
            int row = f / 12, c12 = f % 12;
            *(float4*)&Bh[row * 104 + c12 * 8] =
                *(const float4*)(Bh_g + (size_t)(k0 + row) * 96 + c12 * 8);
            *(float4*)&Bl[row * 104 + c12 * 8] =
                *(const float4*)(Bl_g + (size_t)(k0 + row) * 96 + c12 * 8);
        }
#pragma unroll
        for (int m = 0; m < 3; ++m) {
            int f = tid + 256 * m;
            int row = f >> 3, c8 = f & 7;
            *(float4*)&Vt[row * 72 + c8 * 8] =
                *(const float4*)(Vt_g + (size_t)row * 2048 + k0 + c8 * 8);
        }
        __syncthreads();
        f32x4 accS[4] = {}, accX[4] = {};
#pragma unroll
        for (int cc = 0; cc < 3; ++cc) {
            f16x8 bh = *(const f16x8*)&Bh[(w * 16 + l15) * 104 + cc * 32 + quad * 8];
            f16x8 bl = *(const f16x8*)&Bl[(w * 16 + l15) * 104 + cc * 32 + quad * 8];
#pragma unroll
            for (int mt = 0; mt < 4; ++mt) {
                accS[mt] = MFMA16(Afh[mt][cc], bh, accS[mt]);
                accX[mt] = MFMA16(Afh[mt][cc], bl, accX[mt]);
                accX[mt] = MFMA16(Afl[mt][cc], bh, accX[mt]);
            }
        }
#pragma unroll
        for (int mt = 0; mt < 4; ++mt)
#pragma unroll
            for (int r = 0; r < 4; ++r) {
                float z = 768.0f * (accS[mt][r] + accX[mt][r] * INV2048);
                P[(16 * mt + 4 * quad + r) * 72 + w * 16 + l15] =
                    (f16)__expf(z + negM[mt][r]);
            }
        __syncthreads();
#pragma unroll
        for (int kc = 0; kc < 2; ++kc) {
            f16x8 ap = *(const f16x8*)&P[(w * 16 + l15) * 72 + kc * 32 + quad * 8];
#pragma unroll
            for (int nt = 0; nt < 6; ++nt) {
                f16x8 bv = *(const f16x8*)&Vt[(nt * 16 + l15) * 72 + kc * 32 + quad * 8];
                accO[nt] = MFMA16(ap, bv, accO[nt]);
            }
        }
        __syncthreads();
    }
    const int b = head >> 3, c = head & 7;
#pragma unroll
    for (int r = 0; r < 4; ++r) {
        int q = q0 + w * 16 + quad * 4 + r;
        int cbi = (b * 2048 + q) * 96;
        f16* wrow = w1 + (size_t)(b * 2048 + q) * 768 + c * 96;
#pragma unroll
        for (int nt = 0; nt < 3; ++nt) {
            int rr = nt * 16 + l15;
            float cc = cosb[cbi + rr], ss = sinb[cbi + rr];
            float a = accO[nt][r] * invL[r];
            float b2 = accO[nt + 3][r] * invL[r];
            wrow[rr] = (f16)(a * cc + b2 * ss);
            wrow[rr + 48] = (f16)(b2 * cc - a * ss);
        }
    }
}

// ============================================================
// K3b: S2[q][k]=vr_q.ur_k (bitwise == k2's z transposed),
// P2=exp(z-M[k])/L[k], out=P2@uo, rope -> w2 (f16).
// ============================================================
__global__ __launch_bounds__(256, 2) void k3b(const f16* __restrict__ uhp,
                                              const f16* __restrict__ ulp,
                                              const f16* __restrict__ vhp,
                                              const f16* __restrict__ vlp,
                                              const f16* __restrict__ oT,
                                              const float* __restrict__ Mo,
                                              const float* __restrict__ Lo,
                                              const float* __restrict__ cosb,
                                              const float* __restrict__ sinb,
                                              f16* __restrict__ w2) {
    __shared__ f16 Bh[64 * 104];
    __shared__ f16 Bl[64 * 104];
    __shared__ f16 Ot[96 * 72];
    __shared__ f16 P[64 * 72];
    const int tid = threadIdx.x, w = tid >> 6, lane = tid & 63;
    const int quad = lane >> 4, l15 = lane & 15;
    const int q0 = blockIdx.x * 64, head = blockIdx.y;
    const f16* Ah_g = vhp + (size_t)head * 2048 * 96;   // A = vr
    const f16* Al_g = vlp + (size_t)head * 2048 * 96;
    const f16* Bh_g = uhp + (size_t)head * 2048 * 96;   // B = ur
    const f16* Bl_g = ulp + (size_t)head * 2048 * 96;
    const f16* Ot_g = oT + (size_t)head * 96 * 2048;

    f16x8 Afh[4][3], Afl[4][3];
#pragma unroll
    for (int mt = 0; mt < 4; ++mt)
#pragma unroll
        for (int cc = 0; cc < 3; ++cc) {
            size_t off = (size_t)(q0 + 16 * mt + l15) * 96 + cc * 32 + quad * 8;
            Afh[mt][cc] = *(const f16x8*)(Ah_g + off);
            Afl[mt][cc] = *(const f16x8*)(Al_g + off);
        }

    f32x4 accO[6] = {};

    for (int k0 = 0; k0 < 2048; k0 += 64) {
        float negMk = -Mo[head * 2048 + k0 + w * 16 + l15];
        float invLk = 1.0f / Lo[head * 2048 + k0 + w * 16 + l15];
        __syncthreads();
#pragma unroll
        for (int m = 0; m < 3; ++m) {
            int f = tid + 256 * m;
            int row = f / 12, c12 = f % 12;
            *(float4*)&Bh[row * 104 + c12 * 8] =
                *(const float4*)(Bh_g + (size_t)(k0 + row) * 96 + c12 * 8);
            *(float4*)&Bl[row * 104 + c12 * 8] =
                *(const float4*)(Bl_g + (size_t)(k0 + row) * 96 + c12 * 8);
        }
#pragma unroll
        for (int m = 0; m < 3; ++m) {
            int f = tid + 256 * m;
            int row = f >> 3, c8 = f & 7;
            *(float4*)&Ot[row * 72 + c8 * 8] =
                *(const float4*)(Ot_g + (size_t)row * 2048 + k0 + c8 * 8);
        }
        __syncthreads();
        f32x4 accS[4] = {}, accX[4] = {};
#pragma unroll
        for (int cc = 0; cc < 3; ++cc) {
            f16x8 bh = *(const f16x8*)&Bh[(w * 16 + l15) * 104 + cc * 32 + quad * 8];
            f16x8 bl = *(const f16x8*)&Bl[(w * 16 + l15) * 104 + cc * 32 + quad * 8];
#pragma unroll
            for (int mt = 0; mt < 4; ++mt) {
                accS[mt] = MFMA16(Afh[mt][cc], bh, accS[mt]);
                // preserve k2's cross-product order: (u_hi*v_lo) first, then (u_lo*v_hi)
                accX[mt] = MFMA16(Afl[mt][cc], bh, accX[mt]);   // v_lo * u_hi
                accX[mt] = MFMA16(Afh[mt][cc], bl, accX[mt]);   // v_hi * u_lo
            }
        }
#pragma unroll
        for (int mt = 0; mt < 4; ++mt)
#pragma unroll
            for (int r = 0; r < 4; ++r) {
                float z = 768.0f * (accS[mt][r] + accX[mt][r] * INV2048);
                P[(16 * mt + 4 * quad + r) * 72 + w * 16 + l15] =
                    (f16)(__expf(z + negMk) * invLk);
            }
        __syncthreads();
#pragma unroll
        for (int kc = 0; kc < 2; ++kc) {
            f16x8 ap = *(const f16x8*)&P[(w * 16 + l15) * 72 + kc * 32 + quad * 8];
#pragma unroll
            for (int nt = 0; nt < 6; ++nt) {
                f16x8 bo = *(const f16x8*)&Ot[(nt * 16 + l15) * 72 + kc * 32 + quad * 8];
                accO[nt] = MFMA16(ap, bo, accO[nt]);
            }
        }
        __syncthreads();
    }
    const int b = head >> 3, c = head & 7;
#pragma unroll
    for (int r = 0; r < 4; ++r) {
        int q = q0 + w * 16 + quad * 4 + r;
        int cbi = (b * 2048 + q) * 96;
        f16* wrow = w2 + (size_t)(b * 2048 + q) * 768 + c * 96;
#pragma unroll
        for (int nt = 0; nt < 3; ++nt) {
            int rr = nt * 16 + l15;
            float cc = cosb[cbi + rr], ss = sinb[cbi + rr];
            float a = accO[nt][r];
            float b2 = accO[nt + 3][r];
            wrow[rr] = (f16)(a * cc - b2 * ss);
            wrow[rr + 48] = (f16)(b2 * cc + a * ss);
        }
    }
}

// ============================================================
// K4: G = w1@U + w2@V (fp16 MFMA). grid (32 s-blocks, 12 d-blocks),
// block 256 (4 waves), tile 128s x 64d, wave strip 32s.
// ============================================================
__global__ __launch_bounds__(256, 2) void k4_final(const f16* __restrict__ w1,
                                                   const f16* __restrict__ w2,
                                                   const float* __restrict__ U,
                                                   const float* __restrict__ V,
                                                   float* __restrict__ outp) {
    __shared__ f16 A1[128 * 56];
    __shared__ f16 A2[128 * 56];
    __shared__ f16 B1[64 * 56];
    __shared__ f16 B2[64 * 56];
    const int tid = threadIdx.x, w = tid >> 6, lane = tid & 63;
    const int quad = lane >> 4, l15 = lane & 15;
    const int bs0 = blockIdx.x * 128;
    const int d0 = blockIdx.y * 64;
    f32x4 acc[2][4] = {};

    for (int ec = 0; ec < 24; ++ec) {
        int e0 = ec * 32;
        __syncthreads();
#pragma unroll
        for (int m = 0; m < 2; ++m) {
            int f = tid + 256 * m;
            int row = f >> 2, q = f & 3;
            *(float4*)&A1[row * 56 + q * 8] =
                *(const float4*)(w1 + (size_t)(bs0 + row) * 768 + e0 + q * 8);
            *(float4*)&A2[row * 56 + q * 8] =
                *(const float4*)(w2 + (size_t)(bs0 + row) * 768 + e0 + q * 8);
        }
#pragma unroll
        for (int m2 = 0; m2 < 2; ++m2) {
            int e_r = (tid >> 4) + 16 * m2;
            int dc = tid & 15;
            float4 fu = *(const float4*)(U + (size_t)(e0 + e_r) * 768 + d0 + dc * 4);
            float4 fv = *(const float4*)(V + (size_t)(e0 + e_r) * 768 + d0 + dc * 4);
            B1[(dc * 4 + 0) * 56 + e_r] = (f16)fu.x;
            B1[(dc * 4 + 1) * 56 + e_r] = (f16)fu.y;
            B1[(dc * 4 + 2) * 56 + e_r] = (f16)fu.z;
            B1[(dc * 4 + 3) * 56 + e_r] = (f16)fu.w;
            B2[(dc * 4 + 0) * 56 + e_r] = (f16)fv.x;
            B2[(dc * 4 + 1) * 56 + e_r] = (f16)fv.y;
            B2[(dc * 4 + 2) * 56 + e_r] = (f16)fv.z;
            B2[(dc * 4 + 3) * 56 + e_r] = (f16)fv.w;
        }
        __syncthreads();
        f16x8 a1f[2], a2f[2];
#pragma unroll
        for (int mt = 0; mt < 2; ++mt) {
            a1f[mt] = *(const f16x8*)&A1[(32 * w + 16 * mt + l15) * 56 + quad * 8];
            a2f[mt] = *(const f16x8*)&A2[(32 * w + 16 * mt + l15) * 56 + quad * 8];
        }
#pragma unroll
        for (int nt = 0; nt < 4; ++nt) {
            f16x8 b1f = *(const f16x8*)&B1[(nt * 16 + l15) * 56 + quad * 8];
            f16x8 b2f = *(const f16x8*)&B2[(nt * 16 + l15) * 56 + quad * 8];
#pragma unroll
            for (int mt = 0; mt < 2; ++mt) {
                acc[mt][nt] = MFMA16(a1f[mt], b1f, acc[mt][nt]);
                acc[mt][nt] = MFMA16(a2f[mt], b2f, acc[mt][nt]);
            }
        }
    }
#pragma unroll
    for (int mt = 0; mt < 2; ++mt)
#pragma unroll
        for (int nt = 0; nt < 4; ++nt)
#pragma unroll
            for (int r = 0; r < 4; ++r) {
                int s = bs0 + 32 * w + 16 * mt + 4 * quad + r;
                int d = d0 + 16 * nt + l15;
                outp[(size_t)s * 768 + d] = acc[mt][nt][r];
            }
}

extern "C" void kernel_launch(void* const* d_in, const int* in_sizes, int n_in,
                              void* d_out, int out_size, void* d_ws, size_t ws_size,
                              hipStream_t stream) {
    const float* qz   = (const float*)d_in[0];
    const float* cosb = (const float*)d_in[1];
    const float* sinb = (const float*)d_in[2];
    const float* U    = (const float*)d_in[3];
    const float* V    = (const float*)d_in[4];
    float* outp = (float*)d_out;

    f16* ws16 = (f16*)d_ws;
    f16* uhp = ws16;
    f16* ulp = ws16 + HN;
    f16* vhp = ws16 + 2 * HN;
    f16* vlp = ws16 + 3 * HN;
    f16* vT  = ws16 + 4 * HN;
    f16* oT  = ws16 + 5 * HN;
    f16* w1  = ws16 + 6 * HN;
    f16* w2  = ws16 + 7 * HN;
    float* Mo = (float*)(ws16 + 8 * HN);
    float* Lo = Mo + 16 * 2048;

    k1_proj<<<dim3(64, 8), 256, 0, stream>>>(qz, U, V, cosb, sinb, uhp, ulp, vhp, vlp, vT, oT);
    k2_stats<<<dim3(32, 16), 256, 0, stream>>>(uhp, ulp, vhp, vlp, Mo, Lo);
    k3a<<<dim3(32, 16), 256, 0, stream>>>(uhp, ulp, vhp, vlp, vT, Mo, Lo, cosb, sinb, w1);
    k3b<<<dim3(32, 16), 256, 0, stream>>>(uhp, ulp, vhp, vlp, oT, Mo, Lo, cosb, sinb, w2);
    k4_final<<<dim3(32, 12), 256, 0, stream>>>(w1, w2, U, V, outp);
}